// Round 7
// baseline (477.392 us; speedup 1.0000x reference)
//
#include <hip/hip_runtime.h>

typedef unsigned short u16;
typedef unsigned int   u32;
typedef __attribute__((ext_vector_type(4))) float  f32x4;
typedef __attribute__((ext_vector_type(8))) __bf16 bf16x8;

// ---------------- constants ----------------
#define BATCH 8
#define SEQ   2048
#define DMODEL 1024
#define DK    512
#define DV    512
#define SCALE 0.044194173824159216f

__device__ __forceinline__ u16 f2bf(float f) {
  u32 u = __float_as_uint(f);
  return (u16)((u + 0x7fffu + ((u >> 16) & 1u)) >> 16);
}

// mask dtype mode: 0 = int32, 1 = uint8, 2 = float32
__device__ __forceinline__ bool read_mask(const void* p, int idx, int mode) {
  if (mode == 1) return ((const unsigned char*)p)[idx] != 0;
  if (mode == 2) return ((const float*)p)[idx] != 0.0f;
  return ((const int*)p)[idx] != 0;
}

// async global->LDS, 16B per lane, dest = lds + lane*16 (wave-uniform base)
__device__ __forceinline__ void gl_lds16(const u16* g, u16* l) {
  __builtin_amdgcn_global_load_lds(
      (const __attribute__((address_space(1))) u32*)g,
      (__attribute__((address_space(3))) u32*)l, 16, 0, 0);
}

// ---------------- kernel 0: detect mask dtype ----------------
__global__ void detect_mode(const int* __restrict__ qp, int* __restrict__ flag) {
  __shared__ int f;
  if (threadIdx.x == 0) f = 0;
  __syncthreads();
  int local = 0;
  for (int i = threadIdx.x; i < 4096; i += 256) {
    int v = qp[i];
    if (v == 0x3F800000) local |= 2;
    else if (v != 0 && v != 1 && v != -1) local |= 1;
  }
  if (local) atomicOr(&f, local);
  __syncthreads();
  if (threadIdx.x == 0) {
    int m = 0;
    if (f & 2) m = 2; else if (f & 1) m = 1;
    *flag = m;
  }
}

// ---------------- kernel 1: W [1024][512] f32 -> Wt [512][1024] bf16 ----------------
__global__ __launch_bounds__(256) void wt_transpose(const float* __restrict__ W0,
                                                    const float* __restrict__ W1,
                                                    const float* __restrict__ W2,
                                                    u16* __restrict__ dst) {
  const float* W = (blockIdx.z == 0) ? W0 : (blockIdx.z == 1) ? W1 : W2;
  u16* out = dst + (size_t)blockIdx.z * (DK * DMODEL);
  __shared__ float T[32][33];
  int k0 = blockIdx.x * 32, n0 = blockIdx.y * 32;
  int tx = threadIdx.x, ty = threadIdx.y;
#pragma unroll
  for (int i = 0; i < 4; ++i) {
    int r = ty + i * 8;
    T[r][tx] = W[(size_t)(k0 + r) * DK + n0 + tx];
  }
  __syncthreads();
#pragma unroll
  for (int i = 0; i < 4; ++i) {
    int r = ty + i * 8;
    out[(size_t)(n0 + r) * DMODEL + k0 + tx] = f2bf(T[tx][r]);
  }
}

// ---------------- kernel 2: f32 -> bf16 elementwise (A pre-convert) ----------------
__global__ __launch_bounds__(256) void convert_bf16(const float* __restrict__ src,
                                                    u16* __restrict__ dst) {
  int i = (blockIdx.x * 256 + threadIdx.x) * 8;
  f32x4 a = *(const f32x4*)(src + i);
  f32x4 b = *(const f32x4*)(src + i + 4);
  uint4 o;
  o.x = (u32)f2bf(a[0]) | ((u32)f2bf(a[1]) << 16);
  o.y = (u32)f2bf(a[2]) | ((u32)f2bf(a[3]) << 16);
  o.z = (u32)f2bf(b[0]) | ((u32)f2bf(b[1]) << 16);
  o.w = (u32)f2bf(b[2]) | ((u32)f2bf(b[3]) << 16);
  *(uint4*)(dst + i) = o;
}

// ---------------- kernel 3: projection GEMM (m97 structure) ----------------
// C[16384][512] = A(bf16)[16384][1024] * Wt(bf16)[512][1024]^T
// 128x128 tile, BK=64, global_load_lds w=16, XOR-8 LDS swizzle.
// Epilogue writes MFMA-fragment layouts:
//   Qf/Kf (is_v=0): off(row,d) = (row>>4)*8192 + (d>>5)*512 + (row&15)*32 + (d&31)
//   Vf    (is_v=1): off(dv,s)  = b*S*DV + (dv>>4)*32768 + (s>>5)*512 + (dv&15)*32 + (s&31)
__global__ __launch_bounds__(256, 3) void proj_gemm(const u16* __restrict__ A,
                                                    const u16* __restrict__ Wt_base,
                                                    int z0, u16* __restrict__ dst0,
                                                    u16* __restrict__ dst1) {
  int z = z0 + blockIdx.z;
  const u16* Wt = Wt_base + (size_t)z * (DK * DMODEL);
  u16* dst = (z == 2) ? dst1 : dst0;
  int n0 = blockIdx.x * 128, m0 = blockIdx.y * 128;

  __shared__ __align__(16) u16 As[128 * 64];
  __shared__ __align__(16) u16 Bs[128 * 64];

  int tid = threadIdx.x, lane = tid & 63, w = tid >> 6;
  int wm = w & 1, wn = w >> 1;
  int l15 = lane & 15, lg = lane >> 4;
  int r3 = lane >> 3, c7 = lane & 7;
  int csw = c7 ^ r3;               // swizzled global chunk for this lane

  f32x4 acc[4][4];
#pragma unroll
  for (int m = 0; m < 4; ++m)
#pragma unroll
    for (int n = 0; n < 4; ++n) acc[m][n] = (f32x4)0.0f;

  for (int k0 = 0; k0 < DMODEL; k0 += 64) {
    __syncthreads(); // prior frag reads done
#pragma unroll
    for (int u = 0; u < 4; ++u) {
      int t = w * 4 + u; // instr covers rows t*8 .. t*8+7
      gl_lds16(A  + (size_t)(m0 + t * 8 + r3) * DMODEL + k0 + csw * 8, &As[t * 512]);
      gl_lds16(Wt + (size_t)(n0 + t * 8 + r3) * DMODEL + k0 + csw * 8, &Bs[t * 512]);
    }
    __syncthreads(); // drain
#pragma unroll
    for (int ks = 0; ks < 2; ++ks) {
      bf16x8 af[4], bfv[4];
#pragma unroll
      for (int m = 0; m < 4; ++m) {
        int row = wm * 64 + m * 16 + l15;
        af[m] = *(const bf16x8*)&As[row * 64 + (((ks * 4 + lg) ^ (l15 & 7)) * 8)];
      }
#pragma unroll
      for (int n = 0; n < 4; ++n) {
        int row = wn * 64 + n * 16 + l15;
        bfv[n] = *(const bf16x8*)&Bs[row * 64 + (((ks * 4 + lg) ^ (l15 & 7)) * 8)];
      }
#pragma unroll
      for (int m = 0; m < 4; ++m)
#pragma unroll
        for (int n = 0; n < 4; ++n)
          acc[m][n] = __builtin_amdgcn_mfma_f32_16x16x32_bf16(af[m], bfv[n], acc[m][n], 0, 0, 0);
    }
  }

  if (z != 2) {
    // Qf/Kf fragment layout (global row carries batch: b*S*DK == (row>>4)*8192 base)
#pragma unroll
    for (int m = 0; m < 4; ++m) {
      int rowb = m0 + wm * 64 + m * 16;
#pragma unroll
      for (int n = 0; n < 4; ++n) {
        int col = n0 + wn * 64 + n * 16 + l15;
        size_t base = (size_t)(rowb >> 4) * 8192 + (size_t)(col >> 5) * 512 + (col & 31);
#pragma unroll
        for (int r = 0; r < 4; ++r)
          dst[base + (lg * 4 + r) * 32] = f2bf(acc[m][n][r]);
      }
    }
  } else {
    // Vf fragment layout (transposed): pack 4 consecutive s into one 8B store
#pragma unroll
    for (int m = 0; m < 4; ++m) {
      int row0 = m0 + wm * 64 + m * 16 + lg * 4;
      int b = row0 >> 11, s0 = row0 & 2047;
#pragma unroll
      for (int n = 0; n < 4; ++n) {
        int dv = n0 + wn * 64 + n * 16 + l15;
        size_t off = (size_t)b * (SEQ * DV) + (size_t)(dv >> 4) * 32768 +
                     (size_t)(s0 >> 5) * 512 + (dv & 15) * 32 + (s0 & 31);
        u16 tmp[4] __attribute__((aligned(8)));
#pragma unroll
        for (int r = 0; r < 4; ++r) tmp[r] = f2bf(acc[m][n][r]);
        *(uint2*)&dst[off] = *(const uint2*)tmp;
      }
    }
  }
}

// ---------------- kernel 4: flash attention, 32-row pair-fused blocks ----------
// r6 post-mortem: 16-row blocks are L2/L3-BW bound (2.2 GB K/V re-reads, 21 B/cy/CU
// effective). Halve traffic: 32 q-rows per block. 512 threads (clean-compile
// regime), pair {63-c, c} -> uniform 33 K-tiles of Tk=64 per block. Grid 256 =
// 1 block/CU (8 waves). V-prefetch into regs right after S-MFMA hides V's L2
// latency under softmax+barriers.
// S phase:  wave w -> m-frag mS=w>>2, key 16-slice wk=w&3. Q in LDS (swizzled).
// PV phase: wave w -> dv slice w*64, both m-frags; V from prefetch regs.
// b = bi&7 pins each batch to one XCD (K+V = 4MB = L2).
__global__ __launch_bounds__(512, 4) void attn_kernel(
    const u16* __restrict__ Qf, const u16* __restrict__ Kf,
    const u16* __restrict__ Vf, const void* __restrict__ qpad,
    const void* __restrict__ kvpad, const int* __restrict__ flag,
    float* __restrict__ out) {
  __shared__ __align__(16) u16 Qs[32 * 512];    // Q tile, 32KB, swizzled 16B slots
  __shared__ __align__(16) u16 Pbuf[32 * 72];   // 32 rows x 64 keys, stride 72
  __shared__ __align__(16) float partm[32 * 4];
  __shared__ __align__(16) float partl[32 * 4];
  __shared__ __align__(16) float ald[32];

  int tid = threadIdx.x;
  int lane = tid & 63, w = tid >> 6;           // w in 0..7
  int l15 = lane & 15, lg = lane >> 4;
  int wk = w & 3;        // key 16-slice in S phase (Tk=64)
  int mS = w >> 2;       // S-phase m-frag
  int bi = blockIdx.x;
  int b = bi & 7, c = bi >> 3;                 // batch -> XCD locality, c in 0..31
  int mode = *flag;
  int lanoff = l15 * 32 + lg * 8;
  // swizzled offsets (u16 units): read slot sigma(s), staging source sigma(lane)
  int qswz = (((l15 * 4 + lg) ^ (l15 >> 1)) * 8);
  int sswz = ((lane ^ ((lane >> 3) & 7)) * 8);

  const u16* Qb = Qf + (size_t)b * (SEQ * DK);
  const u16* Kb = Kf + (size_t)b * (SEQ * DK);
  const u16* Vb = Vf + (size_t)b * (SEQ * DV);

#pragma unroll 1
  for (int pass = 0; pass < 2; ++pass) {
    int qt = pass ? c : (63 - c);              // expensive tile first
    int q0 = qt * 32;

    // ---- stage Q tile into LDS: 64 chunks of 1KB, 8 instrs/wave ----
    {
      const u16* qsrc = Qb + (size_t)qt * 16384 + sswz;
#pragma unroll
      for (int u = 0; u < 8; ++u) {
        int i = w * 8 + u;
        gl_lds16(qsrc + i * 512, &Qs[i * 512]);
      }
    }

    f32x4 o[2][4];
#pragma unroll
    for (int mf = 0; mf < 2; ++mf)
#pragma unroll
      for (int n = 0; n < 4; ++n) o[mf][n] = (f32x4)0.0f;

    float mo[4], lsum[4];
#pragma unroll
    for (int r = 0; r < 4; ++r) { mo[r] = -1e38f; lsum[r] = 0.0f; }

    int nkt = (q0 + 95) >> 6;                  // ceil((q0+32)/64); pair-sum = 33
    __syncthreads(); // Q staged (drains vmcnt); fences prior-pass LDS reads

    for (int kt = 0; kt < nkt; ++kt) {
      int key = (kt << 6) + wk * 16 + l15;
      bool kvm = read_mask(kvpad, b * SEQ + key, mode);

      // ---- S = Q K^T : 16 k-slices, Q from LDS (swizzled), K from global ----
      f32x4 sa = (f32x4)0.0f, sb = (f32x4)0.0f;
      {
        const u16* kp = Kb + (size_t)(kt * 4 + wk) * 8192 + lanoff;
        const u16* qp = &Qs[mS * 8192 + qswz];
#pragma unroll
        for (int ks = 0; ks < 16; ks += 2) {
          bf16x8 qv0 = *(const bf16x8*)(qp + ks * 512);
          bf16x8 kv0 = *(const bf16x8*)(kp + ks * 512);
          bf16x8 qv1 = *(const bf16x8*)(qp + (ks + 1) * 512);
          bf16x8 kv1 = *(const bf16x8*)(kp + (ks + 1) * 512);
          sa = __builtin_amdgcn_mfma_f32_16x16x32_bf16(qv0, kv0, sa, 0, 0, 0);
          sb = __builtin_amdgcn_mfma_f32_16x16x32_bf16(qv1, kv1, sb, 0, 0, 0);
        }
      }

      // ---- V prefetch (dv slice w*64, this tile's 64 keys): latency hides
      //      under mask/shuffle/B1/softmax/B2 ----
      bf16x8 vpre[8];
      {
        const u16* vp = Vb + (size_t)(w * 4) * 32768 + (size_t)(kt * 2) * 512 + lanoff;
#pragma unroll
        for (int n = 0; n < 4; ++n)
#pragma unroll
          for (int ks2 = 0; ks2 < 2; ++ks2)
            vpre[n * 2 + ks2] = *(const bf16x8*)(vp + (size_t)n * 32768 + ks2 * 512);
      }

      // ---- scale + mask ----
      float sv[4];
#pragma unroll
      for (int r = 0; r < 4; ++r) {
        int qrow = q0 + mS * 16 + lg * 4 + r;
        float x = (sa[r] + sb[r]) * SCALE;
        sv[r] = (kvm || key > qrow) ? -__builtin_inff() : x;
      }

      // ---- wave-local row max over this wave's 16 keys ----
      float wmax[4];
#pragma unroll
      for (int r = 0; r < 4; ++r) wmax[r] = sv[r];
#pragma unroll
      for (int d = 1; d < 16; d <<= 1)
#pragma unroll
        for (int r = 0; r < 4; ++r) wmax[r] = fmaxf(wmax[r], __shfl_xor(wmax[r], d));
      if (l15 == 0) {
#pragma unroll
        for (int r = 0; r < 4; ++r) partm[(mS * 16 + lg * 4 + r) * 4 + wk] = wmax[r];
      }
      __syncthreads(); // B1 (also fences prev-tile Pbuf reads vs this tile's writes)

      // ---- online softmax update (own m-frag) ----
      float al[4], ws[4];
#pragma unroll
      for (int r = 0; r < 4; ++r) {
        int row = mS * 16 + lg * 4 + r;
        f32x4 pm = *(const f32x4*)&partm[row * 4];
        float tm = fmaxf(fmaxf(pm[0], pm[1]), fmaxf(pm[2], pm[3]));
        float mn = fmaxf(mo[r], fmaxf(tm, -1e38f));
        al[r] = __expf(mo[r] - mn);
        mo[r] = mn;
        float p = __expf(sv[r] - mn);
        Pbuf[row * 72 + wk * 16 + l15] = f2bf(p);
        ws[r] = p;
      }
#pragma unroll
      for (int d = 1; d < 16; d <<= 1)
#pragma unroll
        for (int r = 0; r < 4; ++r) ws[r] += __shfl_xor(ws[r], d);
#pragma unroll
      for (int r = 0; r < 4; ++r) lsum[r] = lsum[r] * al[r] + ws[r];
      if (wk == 0 && l15 == 0) {
#pragma unroll
        for (int r = 0; r < 4; ++r) ald[mS * 16 + lg * 4 + r] = al[r];
      }
      __syncthreads(); // B2: Pbuf + ald visible

      // ---- rescale O (both m-frags, al broadcast via LDS) ----
      float ar[2][4];
#pragma unroll
      for (int mf = 0; mf < 2; ++mf)
#pragma unroll
        for (int r = 0; r < 4; ++r) ar[mf][r] = ald[mf * 16 + lg * 4 + r];
#pragma unroll
      for (int mf = 0; mf < 2; ++mf)
#pragma unroll
        for (int n = 0; n < 4; ++n)
#pragma unroll
          for (int r = 0; r < 4; ++r) o[mf][n][r] *= ar[mf][r];

      // ---- O += P V : P from LDS, V from prefetch regs ----
      {
        bf16x8 pa0[2], pa1[2];
#pragma unroll
        for (int ks2 = 0; ks2 < 2; ++ks2) {
          pa0[ks2] = *(const bf16x8*)&Pbuf[l15 * 72 + ks2 * 32 + lg * 8];
          pa1[ks2] = *(const bf16x8*)&Pbuf[(16 + l15) * 72 + ks2 * 32 + lg * 8];
        }
#pragma unroll
        for (int n = 0; n < 4; ++n)
#pragma unroll
          for (int ks2 = 0; ks2 < 2; ++ks2) {
            o[0][n] = __builtin_amdgcn_mfma_f32_16x16x32_bf16(pa0[ks2], vpre[n * 2 + ks2], o[0][n], 0, 0, 0);
            o[1][n] = __builtin_amdgcn_mfma_f32_16x16x32_bf16(pa1[ks2], vpre[n * 2 + ks2], o[1][n], 0, 0, 0);
          }
      }
    }

    // ---- epilogue for this pass ----
    if (l15 == 0) {
#pragma unroll
      for (int r = 0; r < 4; ++r) partl[(mS * 16 + lg * 4 + r) * 4 + wk] = lsum[r];
    }
    __syncthreads();
    {
      float f[2][4];
#pragma unroll
      for (int mf = 0; mf < 2; ++mf)
#pragma unroll
        for (int r = 0; r < 4; ++r) {
          int row = mf * 16 + lg * 4 + r;
          f32x4 a = *(const f32x4*)&partl[row * 4];
          float l = (a[0] + a[1]) + (a[2] + a[3]);
          bool qp = read_mask(qpad, b * SEQ + q0 + row, mode);
          f[mf][r] = (l > 0.0f && !qp) ? 1.0f / l : 0.0f;
        }
#pragma unroll
      for (int mf = 0; mf < 2; ++mf)
#pragma unroll
        for (int n = 0; n < 4; ++n) {
          int dv = w * 64 + n * 16 + l15;
#pragma unroll
          for (int r = 0; r < 4; ++r) {
            int row = mf * 16 + lg * 4 + r;
            out[(size_t)(b * SEQ + q0 + row) * DV + dv] = o[mf][n][r] * f[mf][r];
          }
        }
    }
    __syncthreads(); // partl/Qs reads done before next pass restages LDS
  }
}

// ---------------- workspace layout (bytes), overlay to stay <= ~87 MB ----------------
// Abf  [16384][1024] bf16 : 0         .. 33554432   (sq first, then skv - reused)
// Qf                      : 33554432  .. 50331648
// Kf                      : 50331648  .. 67108864
// Vf                      : 67108864  .. 83886080
// Wt (3x [512][1024] bf16): 83886080  .. 87031808
// flag (int)              : 87031808  .. 87031812
extern "C" void kernel_launch(void* const* d_in, const int* in_sizes, int n_in,
                              void* d_out, int out_size, void* d_ws, size_t ws_size,
                              hipStream_t stream) {
  const float* sq  = (const float*)d_in[0];
  const float* skv = (const float*)d_in[1];
  const void* qp   = d_in[2];
  const void* kvp  = d_in[3];
  const float* Wq  = (const float*)d_in[4];
  const float* Wk  = (const float*)d_in[5];
  const float* Wv  = (const float*)d_in[6];
  char* ws = (char*)d_ws;

  u16* Abf = (u16*)ws;
  u16* Qf  = (u16*)(ws + 33554432);
  u16* Kf  = (u16*)(ws + 50331648);
  u16* Vf  = (u16*)(ws + 67108864);
  u16* Wt  = (u16*)(ws + 83886080);
  int* flag = (int*)(ws + 87031808);

  wt_transpose<<<dim3(32, 16, 3), dim3(32, 8, 1), 0, stream>>>(Wq, Wk, Wv, Wt);
  detect_mode<<<1, 256, 0, stream>>>((const int*)qp, flag);

  // sq -> Abf, project Q
  convert_bf16<<<8192, 256, 0, stream>>>(sq, Abf);
  proj_gemm<<<dim3(4, 128, 1), dim3(256), 0, stream>>>(Abf, Wt, 0, Qf, Qf);

  // skv -> Abf (reuse), project K and V in one launch (z = 1, 2)
  convert_bf16<<<8192, 256, 0, stream>>>(skv, Abf);
  proj_gemm<<<dim3(4, 128, 2), dim3(256), 0, stream>>>(Abf, Wt, 1, Kf, Vf);

  attn_kernel<<<dim3(256), dim3(512), 0, stream>>>(Qf, Kf, Vf, qp, kvp, flag,
                                                   (float*)d_out);
}

// Round 8
// 400.767 us; speedup vs baseline: 1.1912x; 1.1912x over previous
//
#include <hip/hip_runtime.h>

typedef unsigned short u16;
typedef unsigned int   u32;
typedef __attribute__((ext_vector_type(4))) float  f32x4;
typedef __attribute__((ext_vector_type(8))) __bf16 bf16x8;

// ---------------- constants ----------------
#define BATCH 8
#define SEQ   2048
#define DMODEL 1024
#define DK    512
#define DV    512
#define SCALE 0.044194173824159216f

__device__ __forceinline__ u16 f2bf(float f) {
  u32 u = __float_as_uint(f);
  return (u16)((u + 0x7fffu + ((u >> 16) & 1u)) >> 16);
}

// mask dtype mode: 0 = int32, 1 = uint8, 2 = float32
__device__ __forceinline__ bool read_mask(const void* p, int idx, int mode) {
  if (mode == 1) return ((const unsigned char*)p)[idx] != 0;
  if (mode == 2) return ((const float*)p)[idx] != 0.0f;
  return ((const int*)p)[idx] != 0;
}

// async global->LDS, 16B per lane, dest = lds + lane*16 (wave-uniform base)
__device__ __forceinline__ void gl_lds16(const u16* g, u16* l) {
  __builtin_amdgcn_global_load_lds(
      (const __attribute__((address_space(1))) u32*)g,
      (__attribute__((address_space(3))) u32*)l, 16, 0, 0);
}

// ---------------- kernel 0: detect mask dtype ----------------
__global__ void detect_mode(const int* __restrict__ qp, int* __restrict__ flag) {
  __shared__ int f;
  if (threadIdx.x == 0) f = 0;
  __syncthreads();
  int local = 0;
  for (int i = threadIdx.x; i < 4096; i += 256) {
    int v = qp[i];
    if (v == 0x3F800000) local |= 2;
    else if (v != 0 && v != 1 && v != -1) local |= 1;
  }
  if (local) atomicOr(&f, local);
  __syncthreads();
  if (threadIdx.x == 0) {
    int m = 0;
    if (f & 2) m = 2; else if (f & 1) m = 1;
    *flag = m;
  }
}

// ---------------- kernel 1: W [1024][512] f32 -> Wt [512][1024] bf16 ----------------
__global__ __launch_bounds__(256) void wt_transpose(const float* __restrict__ W0,
                                                    const float* __restrict__ W1,
                                                    const float* __restrict__ W2,
                                                    u16* __restrict__ dst) {
  const float* W = (blockIdx.z == 0) ? W0 : (blockIdx.z == 1) ? W1 : W2;
  u16* out = dst + (size_t)blockIdx.z * (DK * DMODEL);
  __shared__ float T[32][33];
  int k0 = blockIdx.x * 32, n0 = blockIdx.y * 32;
  int tx = threadIdx.x, ty = threadIdx.y;
#pragma unroll
  for (int i = 0; i < 4; ++i) {
    int r = ty + i * 8;
    T[r][tx] = W[(size_t)(k0 + r) * DK + n0 + tx];
  }
  __syncthreads();
#pragma unroll
  for (int i = 0; i < 4; ++i) {
    int r = ty + i * 8;
    out[(size_t)(n0 + r) * DMODEL + k0 + tx] = f2bf(T[tx][r]);
  }
}

// ---------------- kernel 2: f32 -> bf16 elementwise (A pre-convert) ----------------
__global__ __launch_bounds__(256) void convert_bf16(const float* __restrict__ src,
                                                    u16* __restrict__ dst) {
  int i = (blockIdx.x * 256 + threadIdx.x) * 8;
  f32x4 a = *(const f32x4*)(src + i);
  f32x4 b = *(const f32x4*)(src + i + 4);
  uint4 o;
  o.x = (u32)f2bf(a[0]) | ((u32)f2bf(a[1]) << 16);
  o.y = (u32)f2bf(a[2]) | ((u32)f2bf(a[3]) << 16);
  o.z = (u32)f2bf(b[0]) | ((u32)f2bf(b[1]) << 16);
  o.w = (u32)f2bf(b[2]) | ((u32)f2bf(b[3]) << 16);
  *(uint4*)(dst + i) = o;
}

// ---------------- kernel 3: projection GEMM (m97 structure) ----------------
// C[16384][512] = A(bf16)[16384][1024] * Wt(bf16)[512][1024]^T
// 128x128 tile, BK=64, global_load_lds w=16, XOR-8 LDS swizzle.
// Epilogue writes MFMA-fragment layouts:
//   Qf/Kf (is_v=0): off(row,d) = (row>>4)*8192 + (d>>5)*512 + (row&15)*32 + (d&31)
//   Vf    (is_v=1): off(dv,s)  = b*S*DV + (dv>>4)*32768 + (s>>5)*512 + (dv&15)*32 + (s&31)
__global__ __launch_bounds__(256, 3) void proj_gemm(const u16* __restrict__ A,
                                                    const u16* __restrict__ Wt_base,
                                                    int z0, u16* __restrict__ dst0,
                                                    u16* __restrict__ dst1) {
  int z = z0 + blockIdx.z;
  const u16* Wt = Wt_base + (size_t)z * (DK * DMODEL);
  u16* dst = (z == 2) ? dst1 : dst0;
  int n0 = blockIdx.x * 128, m0 = blockIdx.y * 128;

  __shared__ __align__(16) u16 As[128 * 64];
  __shared__ __align__(16) u16 Bs[128 * 64];

  int tid = threadIdx.x, lane = tid & 63, w = tid >> 6;
  int wm = w & 1, wn = w >> 1;
  int l15 = lane & 15, lg = lane >> 4;
  int r3 = lane >> 3, c7 = lane & 7;
  int csw = c7 ^ r3;               // swizzled global chunk for this lane

  f32x4 acc[4][4];
#pragma unroll
  for (int m = 0; m < 4; ++m)
#pragma unroll
    for (int n = 0; n < 4; ++n) acc[m][n] = (f32x4)0.0f;

  for (int k0 = 0; k0 < DMODEL; k0 += 64) {
    __syncthreads(); // prior frag reads done
#pragma unroll
    for (int u = 0; u < 4; ++u) {
      int t = w * 4 + u; // instr covers rows t*8 .. t*8+7
      gl_lds16(A  + (size_t)(m0 + t * 8 + r3) * DMODEL + k0 + csw * 8, &As[t * 512]);
      gl_lds16(Wt + (size_t)(n0 + t * 8 + r3) * DMODEL + k0 + csw * 8, &Bs[t * 512]);
    }
    __syncthreads(); // drain
#pragma unroll
    for (int ks = 0; ks < 2; ++ks) {
      bf16x8 af[4], bfv[4];
#pragma unroll
      for (int m = 0; m < 4; ++m) {
        int row = wm * 64 + m * 16 + l15;
        af[m] = *(const bf16x8*)&As[row * 64 + (((ks * 4 + lg) ^ (l15 & 7)) * 8)];
      }
#pragma unroll
      for (int n = 0; n < 4; ++n) {
        int row = wn * 64 + n * 16 + l15;
        bfv[n] = *(const bf16x8*)&Bs[row * 64 + (((ks * 4 + lg) ^ (l15 & 7)) * 8)];
      }
#pragma unroll
      for (int m = 0; m < 4; ++m)
#pragma unroll
        for (int n = 0; n < 4; ++n)
          acc[m][n] = __builtin_amdgcn_mfma_f32_16x16x32_bf16(af[m], bfv[n], acc[m][n], 0, 0, 0);
    }
  }

  if (z != 2) {
    // Qf/Kf fragment layout (global row carries batch: b*S*DK == (row>>4)*8192 base)
#pragma unroll
    for (int m = 0; m < 4; ++m) {
      int rowb = m0 + wm * 64 + m * 16;
#pragma unroll
      for (int n = 0; n < 4; ++n) {
        int col = n0 + wn * 64 + n * 16 + l15;
        size_t base = (size_t)(rowb >> 4) * 8192 + (size_t)(col >> 5) * 512 + (col & 31);
#pragma unroll
        for (int r = 0; r < 4; ++r)
          dst[base + (lg * 4 + r) * 32] = f2bf(acc[m][n][r]);
      }
    }
  } else {
    // Vf fragment layout (transposed): pack 4 consecutive s into one 8B store
#pragma unroll
    for (int m = 0; m < 4; ++m) {
      int row0 = m0 + wm * 64 + m * 16 + lg * 4;
      int b = row0 >> 11, s0 = row0 & 2047;
#pragma unroll
      for (int n = 0; n < 4; ++n) {
        int dv = n0 + wn * 64 + n * 16 + l15;
        size_t off = (size_t)b * (SEQ * DV) + (size_t)(dv >> 4) * 32768 +
                     (size_t)(s0 >> 5) * 512 + (dv & 15) * 32 + (s0 & 31);
        u16 tmp[4] __attribute__((aligned(8)));
#pragma unroll
        for (int r = 0; r < 4; ++r) tmp[r] = f2bf(acc[m][n][r]);
        *(uint2*)&dst[off] = *(const uint2*)tmp;
      }
    }
  }
}

// ---------------- kernel 4: flash attention, 8-wave pair-fused blocks ----------
// r6 structure (proven 170us clean): 16 q-rows/pass, Tk=128, 512 threads, pair
// {127-c, c} -> uniform 17 K-tiles/block, grid 512 = 2 blocks/CU = 16 waves/CU.
// NEW vs r6:
//  (a) __launch_bounds__(512, 2). Empirically hipcc treats arg2 as CUDA-style
//      min-BLOCKS/CU: (512,4) capped VGPR at 512/(4*8/4)=64 and spilled 150MB
//      (r7); (256,2)->128 (r0). (512,2) -> cap 128, two blocks still resident.
//  (b) V-prefetch: r6 loaded all 16 V frags after barrier B2 (syncthreads
//      blocks hoisting) -> exposed L2 latency in PV every tile. Prefetch 8
//      (ks=0,1; 32 VGPRs, affordable under the 128 cap) right after S-MFMAs so
//      latency hides under max-reduce/B1/softmax/B2; issue ks=2,3 at PV start.
// S phase:  wave w -> key 16-slice w (Tk=128 = 8 slices), single m-frag.
// PV phase: wave w -> dv slice w*64.
// Qs XOR-swizzle sigma(s)=s^((s>>3)&7) on 16B slots (global-source side +
// read side; LDS dest linear). b = bi&7 pins each batch to one XCD.
__global__ __launch_bounds__(512, 2) void attn_kernel(
    const u16* __restrict__ Qf, const u16* __restrict__ Kf,
    const u16* __restrict__ Vf, const void* __restrict__ qpad,
    const void* __restrict__ kvpad, const int* __restrict__ flag,
    float* __restrict__ out) {
  __shared__ __align__(16) u16 Qs[16 * 512];    // Q tile, 16KB, swizzled slots
  __shared__ __align__(16) u16 Pbuf[16 * 136];  // 16 rows x 128 keys, stride 136
  __shared__ __align__(16) float partm[16 * 8];
  __shared__ __align__(16) float partl[16 * 8];

  int tid = threadIdx.x;
  int lane = tid & 63, w = tid >> 6;           // w in 0..7
  int l15 = lane & 15, lg = lane >> 4;
  int bi = blockIdx.x;
  int b = bi & 7, c = bi >> 3;                 // batch -> XCD locality, c in 0..63
  int mode = *flag;
  int lanoff = l15 * 32 + lg * 8;
  // swizzled offsets (u16 units): read slot sigma(s), staging source sigma(lane)
  int qswz = (((l15 * 4 + lg) ^ (l15 >> 1)) * 8);
  int sswz = ((lane ^ ((lane >> 3) & 7)) * 8);

  const u16* Qb = Qf + (size_t)b * (SEQ * DK);
  const u16* Kb = Kf + (size_t)b * (SEQ * DK);
  const u16* Vb = Vf + (size_t)b * (SEQ * DV);

#pragma unroll 1
  for (int pass = 0; pass < 2; ++pass) {
    int qt = pass ? c : (127 - c);             // expensive tile first
    int q0 = qt * 16;

    // ---- stage Q tile into LDS: 16 chunks of 1KB, 2 instrs/wave ----
    {
      const u16* qsrc = Qb + (size_t)qt * 8192 + sswz;
#pragma unroll
      for (int u = 0; u < 2; ++u) {
        int i = w * 2 + u;
        gl_lds16(qsrc + i * 512, &Qs[i * 512]);
      }
    }

    f32x4 o[4];
#pragma unroll
    for (int n = 0; n < 4; ++n) o[n] = (f32x4)0.0f;

    float mo[4], lsum[4];
#pragma unroll
    for (int r = 0; r < 4; ++r) { mo[r] = -1e38f; lsum[r] = 0.0f; }

    int nkt = (q0 + 143) >> 7;                 // ceil((q0+16)/128); pair-sum = 17
    __syncthreads(); // Q staged (drains vmcnt); fences prior-pass LDS reads

    for (int kt = 0; kt < nkt; ++kt) {
      int key = (kt << 7) + w * 16 + l15;
      bool kvm = read_mask(kvpad, b * SEQ + key, mode);

      // ---- S = Q K^T : 16 k-slices, Q from LDS (swizzled), K from global ----
      f32x4 sa = (f32x4)0.0f, sb = (f32x4)0.0f;
      {
        const u16* kp = Kb + (size_t)(kt * 8 + w) * 8192 + lanoff;
#pragma unroll
        for (int ks = 0; ks < 16; ks += 2) {
          bf16x8 qv0 = *(const bf16x8*)&Qs[ks * 512 + qswz];
          bf16x8 kv0 = *(const bf16x8*)(kp + ks * 512);
          bf16x8 qv1 = *(const bf16x8*)&Qs[(ks + 1) * 512 + qswz];
          bf16x8 kv1 = *(const bf16x8*)(kp + (ks + 1) * 512);
          sa = __builtin_amdgcn_mfma_f32_16x16x32_bf16(qv0, kv0, sa, 0, 0, 0);
          sb = __builtin_amdgcn_mfma_f32_16x16x32_bf16(qv1, kv1, sb, 0, 0, 0);
        }
      }

      // ---- V prefetch, first half (ks=0,1 -> keys 0..63 of this tile):
      //      latency hides under mask/max-reduce/B1/softmax/B2 ----
      const u16* vp = Vb + (size_t)(w * 4) * 32768 + (size_t)(kt * 4) * 512 + lanoff;
      bf16x8 vpre[8];
#pragma unroll
      for (int n = 0; n < 4; ++n)
#pragma unroll
        for (int ks2 = 0; ks2 < 2; ++ks2)
          vpre[n * 2 + ks2] = *(const bf16x8*)(vp + (size_t)n * 32768 + ks2 * 512);

      // ---- scale + mask ----
      float sv[4];
#pragma unroll
      for (int r = 0; r < 4; ++r) {
        int qrow = q0 + lg * 4 + r;
        float x = (sa[r] + sb[r]) * SCALE;
        sv[r] = (kvm || key > qrow) ? -__builtin_inff() : x;
      }

      // ---- wave-local row max over this wave's 16 keys ----
      float wmax[4];
#pragma unroll
      for (int r = 0; r < 4; ++r) wmax[r] = sv[r];
#pragma unroll
      for (int d = 1; d < 16; d <<= 1)
#pragma unroll
        for (int r = 0; r < 4; ++r) wmax[r] = fmaxf(wmax[r], __shfl_xor(wmax[r], d));
      if (l15 == 0) {
#pragma unroll
        for (int r = 0; r < 4; ++r) partm[(lg * 4 + r) * 8 + w] = wmax[r];
      }
      __syncthreads(); // B1 (also fences prev-tile Pbuf reads vs this tile's writes)

      // ---- online softmax update (single m-frag) ----
      float al[4], ws[4];
#pragma unroll
      for (int r = 0; r < 4; ++r) {
        int row = lg * 4 + r;
        f32x4 p0 = *(const f32x4*)&partm[row * 8];
        f32x4 p1 = *(const f32x4*)&partm[row * 8 + 4];
        float tm = fmaxf(fmaxf(fmaxf(p0[0], p0[1]), fmaxf(p0[2], p0[3])),
                         fmaxf(fmaxf(p1[0], p1[1]), fmaxf(p1[2], p1[3])));
        float mn = fmaxf(mo[r], fmaxf(tm, -1e38f));
        al[r] = __expf(mo[r] - mn);
        mo[r] = mn;
        float p = __expf(sv[r] - mn);
        Pbuf[row * 136 + w * 16 + l15] = f2bf(p);
        ws[r] = p;
      }
#pragma unroll
      for (int d = 1; d < 16; d <<= 1)
#pragma unroll
        for (int r = 0; r < 4; ++r) ws[r] += __shfl_xor(ws[r], d);
#pragma unroll
      for (int r = 0; r < 4; ++r) lsum[r] = lsum[r] * al[r] + ws[r];
      __syncthreads(); // B2: Pbuf visible

      // ---- rescale O ----
#pragma unroll
      for (int n = 0; n < 4; ++n)
#pragma unroll
        for (int r = 0; r < 4; ++r) o[n][r] *= al[r];

      // ---- O += P V : P from LDS; V ks=0,1 from prefetch regs, ks=2,3
      //      issued here ahead of the MFMAs ----
      {
        bf16x8 pa[4];
#pragma unroll
        for (int ks = 0; ks < 4; ++ks)
          pa[ks] = *(const bf16x8*)&Pbuf[l15 * 136 + ks * 32 + lg * 8];
        bf16x8 vrest[8];
#pragma unroll
        for (int n = 0; n < 4; ++n)
#pragma unroll
          for (int ks2 = 0; ks2 < 2; ++ks2)
            vrest[n * 2 + ks2] = *(const bf16x8*)(vp + (size_t)n * 32768 + (ks2 + 2) * 512);
#pragma unroll
        for (int n = 0; n < 4; ++n) {
          o[n] = __builtin_amdgcn_mfma_f32_16x16x32_bf16(pa[0], vpre[n * 2],     o[n], 0, 0, 0);
          o[n] = __builtin_amdgcn_mfma_f32_16x16x32_bf16(pa[1], vpre[n * 2 + 1], o[n], 0, 0, 0);
          o[n] = __builtin_amdgcn_mfma_f32_16x16x32_bf16(pa[2], vrest[n * 2],    o[n], 0, 0, 0);
          o[n] = __builtin_amdgcn_mfma_f32_16x16x32_bf16(pa[3], vrest[n * 2 + 1], o[n], 0, 0, 0);
        }
      }
    }

    // ---- epilogue for this pass ----
    if (l15 == 0) {
#pragma unroll
      for (int r = 0; r < 4; ++r) partl[(lg * 4 + r) * 8 + w] = lsum[r];
    }
    __syncthreads();
    {
      float f[4];
#pragma unroll
      for (int r = 0; r < 4; ++r) {
        int row = lg * 4 + r;
        f32x4 a = *(const f32x4*)&partl[row * 8];
        f32x4 b2 = *(const f32x4*)&partl[row * 8 + 4];
        float l = (a[0] + a[1] + a[2] + a[3]) + (b2[0] + b2[1] + b2[2] + b2[3]);
        bool qp = read_mask(qpad, b * SEQ + q0 + row, mode);
        f[r] = (l > 0.0f && !qp) ? 1.0f / l : 0.0f;
      }
#pragma unroll
      for (int n = 0; n < 4; ++n) {
        int dv = w * 64 + n * 16 + l15;
#pragma unroll
        for (int r = 0; r < 4; ++r) {
          int row = lg * 4 + r;
          out[(size_t)(b * SEQ + q0 + row) * DV + dv] = o[n][r] * f[r];
        }
      }
    }
    __syncthreads(); // partl reads done before next pass reuses LDS
  }
}

// ---------------- workspace layout (bytes), overlay to stay <= ~87 MB ----------------
// Abf  [16384][1024] bf16 : 0         .. 33554432   (sq first, then skv - reused)
// Qf                      : 33554432  .. 50331648
// Kf                      : 50331648  .. 67108864
// Vf                      : 67108864  .. 83886080
// Wt (3x [512][1024] bf16): 83886080  .. 87031808
// flag (int)              : 87031808  .. 87031812
extern "C" void kernel_launch(void* const* d_in, const int* in_sizes, int n_in,
                              void* d_out, int out_size, void* d_ws, size_t ws_size,
                              hipStream_t stream) {
  const float* sq  = (const float*)d_in[0];
  const float* skv = (const float*)d_in[1];
  const void* qp   = d_in[2];
  const void* kvp  = d_in[3];
  const float* Wq  = (const float*)d_in[4];
  const float* Wk  = (const float*)d_in[5];
  const float* Wv  = (const float*)d_in[6];
  char* ws = (char*)d_ws;

  u16* Abf = (u16*)ws;
  u16* Qf  = (u16*)(ws + 33554432);
  u16* Kf  = (u16*)(ws + 50331648);
  u16* Vf  = (u16*)(ws + 67108864);
  u16* Wt  = (u16*)(ws + 83886080);
  int* flag = (int*)(ws + 87031808);

  wt_transpose<<<dim3(32, 16, 3), dim3(32, 8, 1), 0, stream>>>(Wq, Wk, Wv, Wt);
  detect_mode<<<1, 256, 0, stream>>>((const int*)qp, flag);

  // sq -> Abf, project Q
  convert_bf16<<<8192, 256, 0, stream>>>(sq, Abf);
  proj_gemm<<<dim3(4, 128, 1), dim3(256), 0, stream>>>(Abf, Wt, 0, Qf, Qf);

  // skv -> Abf (reuse), project K and V in one launch (z = 1, 2)
  convert_bf16<<<8192, 256, 0, stream>>>(skv, Abf);
  proj_gemm<<<dim3(4, 128, 2), dim3(256), 0, stream>>>(Abf, Wt, 1, Kf, Vf);

  attn_kernel<<<dim3(512), dim3(512), 0, stream>>>(Qf, Kf, Vf, qp, kvp, flag,
                                                   (float*)d_out);
}